// Round 5
// baseline (1498.233 us; speedup 1.0000x reference)
//
#include <hip/hip_runtime.h>
#include <math.h>

// BN(ch=T) -> LSTM(1->64) -> LSTM(64->64) -> FC+GELU.  B=262144 T=15 H=64.
// v5: v4 + opaque register pins (asm "+v") on all hoisted B-fragments and
//     bias/w0 scalars. Theory: v3/v4's 4.5 GB of excess L2-miss traffic is
//     the compiler REMATERIALIZING these loads inside the t-loop (re-reading
//     L3-resident ws at 3.3 TB/s = the measured binder). An opaque value
//     cannot be re-loaded; it must stay register-resident (spill-to-AGPR is
//     free on the unified file; 256-reg budget >= ~200 demand).
//
// ws float offsets:
//   WS_SS    0     scale[15]@+0, shift[15]@+16
//   WS_B0    32    b_ih0+b_hh0 [256]
//   WS_B1    288   b_ih1+b_hh1 [256]
//   WS_FCT   1024  fcT[u][o] fp32 [64][64]
//   WS_STATS 5200  bn sums[15]@+0, sqsums[15]@+16
//   WS_BF    8192  bf16 B-fragments: 96 chunks x 64 lanes x 8 ushort (96 KB)
//     chunk<32:  L0 (w_hh0^T):  ks=chunk>>4 (K=64: 2), nt=chunk&15
//     chunk>=32: L1 ([w_ih1;w_hh1]^T): ks=(chunk-32)>>4 (K=128: 4), nt=&15
//     elem(lane,j) = B[k=32*ks+8*(lane>>4)+j][n=16*nt+(lane&15)]

typedef __attribute__((ext_vector_type(8))) short short8;
typedef __attribute__((ext_vector_type(4))) float f32x4;

#define PIN(v) asm volatile("" : "+v"(v))

namespace {
constexpr int kB = 262144;
constexpr int kT = 15;
constexpr int WS_SS = 0;
constexpr int WS_B0 = 32;
constexpr int WS_B1 = 288;
constexpr int WS_FCT = 1024;
constexpr int WS_STATS = 5200;
constexpr int WS_BF = 8192;
}  // namespace

__device__ __forceinline__ float sigm(float x) {
  return __builtin_amdgcn_rcpf(1.f + __expf(-x));
}
__device__ __forceinline__ float tanhx(float x) {
  return 1.f - 2.f * __builtin_amdgcn_rcpf(1.f + __expf(2.f * x));
}
__device__ __forceinline__ ushort f2bf(float f) {
  unsigned u = __float_as_uint(f);
  unsigned r = (u + 0x7fffu + ((u >> 16) & 1u)) >> 16;  // RNE
  return (ushort)r;
}

__global__ void prep_kernel(const float* __restrict__ w_hh0,
                            const float* __restrict__ w_ih1,
                            const float* __restrict__ w_hh1,
                            const float* __restrict__ b_ih0,
                            const float* __restrict__ b_hh0,
                            const float* __restrict__ b_ih1,
                            const float* __restrict__ b_hh1,
                            const float* __restrict__ fc_w,
                            float* __restrict__ ws) {
  const int stride = gridDim.x * blockDim.x;
  const int t0 = blockIdx.x * blockDim.x + threadIdx.x;
  ushort* bf = (ushort*)(ws + WS_BF);
  for (int i = t0; i < 96 * 512; i += stride) {
    int chunk = i >> 9, lane = (i >> 3) & 63, j = i & 7;
    float v;
    if (chunk < 32) {
      int ks = chunk >> 4, nt = chunk & 15;
      int k = 32 * ks + 8 * (lane >> 4) + j;
      int n = 16 * nt + (lane & 15);
      v = w_hh0[n * 64 + k];
    } else {
      int c2 = chunk - 32;
      int ks = c2 >> 4, nt = c2 & 15;
      int k = 32 * ks + 8 * (lane >> 4) + j;
      int n = 16 * nt + (lane & 15);
      v = (k < 64) ? w_ih1[n * 64 + k] : w_hh1[n * 64 + (k - 64)];
    }
    bf[i] = f2bf(v);
  }
  for (int i = t0; i < 4096; i += stride) {
    int u = i >> 6, o = i & 63;
    ws[WS_FCT + i] = fc_w[o * 64 + u];
  }
  for (int i = t0; i < 256; i += stride) {
    ws[WS_B0 + i] = b_ih0[i] + b_hh0[i];
    ws[WS_B1 + i] = b_ih1[i] + b_hh1[i];
  }
  for (int i = t0; i < 32; i += stride) ws[WS_STATS + i] = 0.f;
}

// Each thread owns one chunk of 15 consecutive float4s (60 elems = 4 full
// mod-15 periods, chunk-aligned so t-indices are compile-time constants).
__global__ void bn_sums_kernel(const float* __restrict__ x,
                               float* __restrict__ ws) {
  __shared__ float ls[16], lq[16];
  const int tid = threadIdx.x;
  if (tid < 16) { ls[tid] = 0.f; lq[tid] = 0.f; }
  __syncthreads();
  const float4* x4 = (const float4*)x;
  const int c0 = (blockIdx.x * 256 + tid) * 15;
  float s[15], q[15];
#pragma unroll
  for (int t = 0; t < 15; ++t) { s[t] = 0.f; q[t] = 0.f; }
#pragma unroll
  for (int c = 0; c < 15; ++c) {
    float4 v = x4[c0 + c];
    s[(4 * c + 0) % 15] += v.x; q[(4 * c + 0) % 15] += v.x * v.x;
    s[(4 * c + 1) % 15] += v.y; q[(4 * c + 1) % 15] += v.y * v.y;
    s[(4 * c + 2) % 15] += v.z; q[(4 * c + 2) % 15] += v.z * v.z;
    s[(4 * c + 3) % 15] += v.w; q[(4 * c + 3) % 15] += v.w * v.w;
  }
#pragma unroll
  for (int t = 0; t < 15; ++t) {
    atomicAdd(&ls[t], s[t]);
    atomicAdd(&lq[t], q[t]);
  }
  __syncthreads();
  if (tid < 15) {
    atomicAdd(&ws[WS_STATS + tid], ls[tid]);
    atomicAdd(&ws[WS_STATS + 16 + tid], lq[tid]);
  }
}

__global__ void bn_final_kernel(const float* __restrict__ gamma,
                                const float* __restrict__ beta,
                                float* __restrict__ ws) {
  int t = threadIdx.x;
  if (t < 15) {
    const float inv = 1.f / (float)kB;
    float mean = ws[WS_STATS + t] * inv;
    float var = ws[WS_STATS + 16 + t] * inv - mean * mean;
    float sc = gamma[t] * rsqrtf(var + 1e-5f);
    ws[WS_SS + t] = sc;
    ws[WS_SS + 16 + t] = beta[t] - mean * sc;
  }
}

// smem: [0,8192) hcat ushort[32][128] XOR-swizzled; [8192,10368) xs f32[32][17]
// phase-2 alias: [0,8704) h1f float[32][68]
__global__ __attribute__((amdgpu_flat_work_group_size(256, 256),
                          amdgpu_waves_per_eu(2, 2))) void lstm_fused_kernel(
    const float* __restrict__ x, const float* __restrict__ w_ih0,
    const float* __restrict__ fc_b, const float* __restrict__ ws,
    float* __restrict__ out) {
  __shared__ __align__(16) char smem[10368];
  ushort* hc = (ushort*)smem;
  float* xsf = (float*)(smem + 8192);

  const int tid = threadIdx.x;
  const int bm0 = blockIdx.x * 32;
  const int lane = tid & 63;
  const int wv = tid >> 6;
  const int grp = lane >> 4;
  const int l15 = lane & 15;
  const int u = wv * 16 + l15;

  for (int i = tid; i < 32 * kT; i += 256) {
    float v = x[(size_t)bm0 * kT + i];
    int m = i / 15, tt = i - m * 15;
    xsf[m * 17 + tt] = v * ws[WS_SS + tt] + ws[WS_SS + 16 + tt];
  }
  for (int i = tid; i < 2048; i += 256) ((unsigned*)hc)[i] = 0u;

  float b0g[4], b1g[4], w0g[4];
#pragma unroll
  for (int j = 0; j < 4; ++j) {
    b0g[j] = ws[WS_B0 + u + 64 * j];
    b1g[j] = ws[WS_B1 + u + 64 * j];
    w0g[j] = w_ih0[u + 64 * j];
    PIN(b0g[j]);
    PIN(b1g[j]);
    PIN(w0g[j]);
  }
  float c0r[8], c1r[8];
#pragma unroll
  for (int i = 0; i < 8; ++i) { c0r[i] = 0.f; c1r[i] = 0.f; }

  // ---- all B fragments register-resident; PIN makes them opaque so the
  // allocator cannot rematerialize the global loads inside the t-loop ----
  const short8* bfr = (const short8*)(ws + WS_BF);
  short8 bL0[8], bL1[16];
#pragma unroll
  for (int ks = 0; ks < 2; ++ks)
#pragma unroll
    for (int j = 0; j < 4; ++j) {
      bL0[ks * 4 + j] = bfr[(ks * 16 + wv + 4 * j) * 64 + lane];
      PIN(bL0[ks * 4 + j]);
    }
#pragma unroll
  for (int ks = 0; ks < 4; ++ks)
#pragma unroll
    for (int j = 0; j < 4; ++j) {
      bL1[ks * 4 + j] = bfr[(32 + ks * 16 + wv + 4 * j) * 64 + lane];
      PIN(bL1[ks * 4 + j]);
    }

  auto ldA = [&](int mt, int ks) -> short8 {
    int row = l15 + 16 * mt;
    int k0 = (32 * ks + 8 * grp) ^ ((row & 7) << 3);
    return *(const short8*)&hc[row * 128 + k0];
  };

  __syncthreads();

  for (int t = 0; t < kT; ++t) {
    // ---------------- layer 0 ----------------
    f32x4 acc[2][4];
#pragma unroll
    for (int mt = 0; mt < 2; ++mt)
#pragma unroll
      for (int r = 0; r < 4; ++r) {
        float xv = xsf[(16 * mt + 4 * grp + r) * 17 + t];
#pragma unroll
        for (int j = 0; j < 4; ++j) acc[mt][j][r] = fmaf(xv, w0g[j], b0g[j]);
      }
#pragma unroll
    for (int ks = 0; ks < 2; ++ks) {
      short8 a0 = ldA(0, ks);
      short8 a1 = ldA(1, ks);
#pragma unroll
      for (int j = 0; j < 4; ++j) {
        acc[0][j] = __builtin_amdgcn_mfma_f32_16x16x32_bf16(a0, bL0[ks * 4 + j], acc[0][j], 0, 0, 0);
        acc[1][j] = __builtin_amdgcn_mfma_f32_16x16x32_bf16(a1, bL0[ks * 4 + j], acc[1][j], 0, 0, 0);
      }
    }
    __syncthreads();  // L0 A-reads (h0 cols) done before h0_t overwrite
#pragma unroll
    for (int mt = 0; mt < 2; ++mt)
#pragma unroll
      for (int r = 0; r < 4; ++r) {
        int row = 16 * mt + 4 * grp + r;
        float zi = acc[mt][0][r], zf = acc[mt][1][r];
        float zg = acc[mt][2][r], zo = acc[mt][3][r];
        float ig = sigm(zi), fg = sigm(zf), gg = tanhx(zg), og = sigm(zo);
        float c = fmaf(fg, c0r[mt * 4 + r], ig * gg);
        c0r[mt * 4 + r] = c;
        float h = og * tanhx(c);
        hc[row * 128 + (u ^ ((row & 7) << 3))] = f2bf(h);
      }
    __syncthreads();  // h0_t visible (also orders prev-iter h1_t writes)

    // ---------------- layer 1 ----------------
#pragma unroll
    for (int mt = 0; mt < 2; ++mt)
#pragma unroll
      for (int j = 0; j < 4; ++j)
#pragma unroll
        for (int r = 0; r < 4; ++r) acc[mt][j][r] = b1g[j];
#pragma unroll
    for (int ks = 0; ks < 4; ++ks) {
      short8 a0 = ldA(0, ks);
      short8 a1 = ldA(1, ks);
#pragma unroll
      for (int j = 0; j < 4; ++j) {
        acc[0][j] = __builtin_amdgcn_mfma_f32_16x16x32_bf16(a0, bL1[ks * 4 + j], acc[0][j], 0, 0, 0);
        acc[1][j] = __builtin_amdgcn_mfma_f32_16x16x32_bf16(a1, bL1[ks * 4 + j], acc[1][j], 0, 0, 0);
      }
    }
    __syncthreads();  // L1 A-reads done before h1_t overwrite
    float* h1f = (float*)smem;
#pragma unroll
    for (int mt = 0; mt < 2; ++mt)
#pragma unroll
      for (int r = 0; r < 4; ++r) {
        int row = 16 * mt + 4 * grp + r;
        float zi = acc[mt][0][r], zf = acc[mt][1][r];
        float zg = acc[mt][2][r], zo = acc[mt][3][r];
        float ig = sigm(zi), fg = sigm(zf), gg = tanhx(zg), og = sigm(zo);
        float c = fmaf(fg, c1r[mt * 4 + r], ig * gg);
        c1r[mt * 4 + r] = c;
        float h = og * tanhx(c);
        if (t < kT - 1) {
          hc[row * 128 + ((64 + u) ^ ((row & 7) << 3))] = f2bf(h);
        } else {
          h1f[row * 68 + u] = h;
        }
      }
    // no barrier here: next L0 MFMA reads only h0 cols (disjoint from h1
    // writes); h1_t -> next L1 read is ordered by next iter's 2nd barrier.
  }
  __syncthreads();  // h1f visible for FC

  // ---------------- FC + exact-erf GELU (fp32) ----------------
  const float* h1 = (const float*)smem;
  const int o = tid & 63;
  const int ms = tid >> 6;
  float yv[8];
  float fb = fc_b[o];
#pragma unroll
  for (int i = 0; i < 8; ++i) yv[i] = fb;
  for (int u0 = 0; u0 < 64; u0 += 4) {
    float q0 = ws[WS_FCT + (u0 + 0) * 64 + o];
    float q1 = ws[WS_FCT + (u0 + 1) * 64 + o];
    float q2 = ws[WS_FCT + (u0 + 2) * 64 + o];
    float q3 = ws[WS_FCT + (u0 + 3) * 64 + o];
#pragma unroll
    for (int i = 0; i < 8; ++i) {
      const float4 hq = *(const float4*)&h1[(ms * 8 + i) * 68 + u0];
      yv[i] = fmaf(hq.x, q0, yv[i]);
      yv[i] = fmaf(hq.y, q1, yv[i]);
      yv[i] = fmaf(hq.z, q2, yv[i]);
      yv[i] = fmaf(hq.w, q3, yv[i]);
    }
  }
#pragma unroll
  for (int i = 0; i < 8; ++i) {
    float v = yv[i];
    float g = 0.5f * v * (1.f + erff(v * 0.70710678118654752f));
    out[(size_t)(bm0 + ms * 8 + i) * 64 + o] = g;
  }
}

extern "C" void kernel_launch(void* const* d_in, const int* in_sizes, int n_in,
                              void* d_out, int out_size, void* d_ws, size_t ws_size,
                              hipStream_t stream) {
  const float* x = (const float*)d_in[0];
  const float* bn_gamma = (const float*)d_in[1];
  const float* bn_beta = (const float*)d_in[2];
  const float* w_ih0 = (const float*)d_in[3];
  const float* w_hh0 = (const float*)d_in[4];
  const float* b_ih0 = (const float*)d_in[5];
  const float* b_hh0 = (const float*)d_in[6];
  const float* w_ih1 = (const float*)d_in[7];
  const float* w_hh1 = (const float*)d_in[8];
  const float* b_ih1 = (const float*)d_in[9];
  const float* b_hh1 = (const float*)d_in[10];
  const float* fc_w = (const float*)d_in[11];
  const float* fc_b = (const float*)d_in[12];
  float* ws = (float*)d_ws;
  float* out = (float*)d_out;

  hipLaunchKernelGGL(prep_kernel, dim3(64), dim3(256), 0, stream,
                     w_hh0, w_ih1, w_hh1, b_ih0, b_hh0, b_ih1, b_hh1, fc_w, ws);
  hipLaunchKernelGGL(bn_sums_kernel, dim3(256), dim3(256), 0, stream, x, ws);
  hipLaunchKernelGGL(bn_final_kernel, dim3(1), dim3(64), 0, stream,
                     bn_gamma, bn_beta, ws);
  hipLaunchKernelGGL(lstm_fused_kernel, dim3(kB / 32), dim3(256), 0, stream,
                     x, w_ih0, fc_b, ws, out);
}

// Round 6
// 887.676 us; speedup vs baseline: 1.6878x; 1.6878x over previous
//
#include <hip/hip_runtime.h>
#include <math.h>

// BN(ch=T) -> LSTM(1->64) -> LSTM(64->64) -> FC+GELU.  B=262144 T=15 H=64.
// v6: persistent blocks. grid=512 (2 blocks/CU resident), each block handles
//     16 batch-tiles of 32 rows; B-fragments loaded ONCE per block; t-loop
//     and tile-loop kept rolled so the hot loop is small and I$-resident.
//
// ws float offsets:
//   WS_SS    0     scale[15]@+0, shift[15]@+16
//   WS_B0    32    b_ih0+b_hh0 [256]
//   WS_B1    288   b_ih1+b_hh1 [256]
//   WS_FCT   1024  fcT[u][o] fp32 [64][64]
//   WS_STATS 5200  bn sums[15]@+0, sqsums[15]@+16
//   WS_BF    8192  bf16 B-fragments: 96 chunks x 64 lanes x 8 ushort (96 KB)
//     chunk<32:  L0 (w_hh0^T):  ks=chunk>>4 (K=64: 2), nt=chunk&15
//     chunk>=32: L1 ([w_ih1;w_hh1]^T): ks=(chunk-32)>>4 (K=128: 4), nt=&15
//     elem(lane,j) = B[k=32*ks+8*(lane>>4)+j][n=16*nt+(lane&15)]

typedef __attribute__((ext_vector_type(8))) short short8;
typedef __attribute__((ext_vector_type(4))) float f32x4;

namespace {
constexpr int kB = 262144;
constexpr int kT = 15;
constexpr int kTiles = kB / 32;   // 8192
constexpr int kGrid = 512;        // 2 blocks per CU, 16 tiles per block
constexpr int WS_SS = 0;
constexpr int WS_B0 = 32;
constexpr int WS_B1 = 288;
constexpr int WS_FCT = 1024;
constexpr int WS_STATS = 5200;
constexpr int WS_BF = 8192;
}  // namespace

__device__ __forceinline__ float sigm(float x) {
  return __builtin_amdgcn_rcpf(1.f + __expf(-x));
}
__device__ __forceinline__ float tanhx(float x) {
  return 1.f - 2.f * __builtin_amdgcn_rcpf(1.f + __expf(2.f * x));
}
__device__ __forceinline__ ushort f2bf(float f) {
  unsigned u = __float_as_uint(f);
  unsigned r = (u + 0x7fffu + ((u >> 16) & 1u)) >> 16;  // RNE
  return (ushort)r;
}

__global__ void prep_kernel(const float* __restrict__ w_hh0,
                            const float* __restrict__ w_ih1,
                            const float* __restrict__ w_hh1,
                            const float* __restrict__ b_ih0,
                            const float* __restrict__ b_hh0,
                            const float* __restrict__ b_ih1,
                            const float* __restrict__ b_hh1,
                            const float* __restrict__ fc_w,
                            float* __restrict__ ws) {
  const int stride = gridDim.x * blockDim.x;
  const int t0 = blockIdx.x * blockDim.x + threadIdx.x;
  ushort* bf = (ushort*)(ws + WS_BF);
  for (int i = t0; i < 96 * 512; i += stride) {
    int chunk = i >> 9, lane = (i >> 3) & 63, j = i & 7;
    float v;
    if (chunk < 32) {
      int ks = chunk >> 4, nt = chunk & 15;
      int k = 32 * ks + 8 * (lane >> 4) + j;
      int n = 16 * nt + (lane & 15);
      v = w_hh0[n * 64 + k];
    } else {
      int c2 = chunk - 32;
      int ks = c2 >> 4, nt = c2 & 15;
      int k = 32 * ks + 8 * (lane >> 4) + j;
      int n = 16 * nt + (lane & 15);
      v = (k < 64) ? w_ih1[n * 64 + k] : w_hh1[n * 64 + (k - 64)];
    }
    bf[i] = f2bf(v);
  }
  for (int i = t0; i < 4096; i += stride) {
    int u = i >> 6, o = i & 63;
    ws[WS_FCT + i] = fc_w[o * 64 + u];
  }
  for (int i = t0; i < 256; i += stride) {
    ws[WS_B0 + i] = b_ih0[i] + b_hh0[i];
    ws[WS_B1 + i] = b_ih1[i] + b_hh1[i];
  }
  for (int i = t0; i < 32; i += stride) ws[WS_STATS + i] = 0.f;
}

// Each thread owns one chunk of 15 consecutive float4s (60 elems = 4 full
// mod-15 periods, chunk-aligned so t-indices are compile-time constants).
__global__ void bn_sums_kernel(const float* __restrict__ x,
                               float* __restrict__ ws) {
  __shared__ float ls[16], lq[16];
  const int tid = threadIdx.x;
  if (tid < 16) { ls[tid] = 0.f; lq[tid] = 0.f; }
  __syncthreads();
  const float4* x4 = (const float4*)x;
  const int c0 = (blockIdx.x * 256 + tid) * 15;
  float s[15], q[15];
#pragma unroll
  for (int t = 0; t < 15; ++t) { s[t] = 0.f; q[t] = 0.f; }
#pragma unroll
  for (int c = 0; c < 15; ++c) {
    float4 v = x4[c0 + c];
    s[(4 * c + 0) % 15] += v.x; q[(4 * c + 0) % 15] += v.x * v.x;
    s[(4 * c + 1) % 15] += v.y; q[(4 * c + 1) % 15] += v.y * v.y;
    s[(4 * c + 2) % 15] += v.z; q[(4 * c + 2) % 15] += v.z * v.z;
    s[(4 * c + 3) % 15] += v.w; q[(4 * c + 3) % 15] += v.w * v.w;
  }
#pragma unroll
  for (int t = 0; t < 15; ++t) {
    atomicAdd(&ls[t], s[t]);
    atomicAdd(&lq[t], q[t]);
  }
  __syncthreads();
  if (tid < 15) {
    atomicAdd(&ws[WS_STATS + tid], ls[tid]);
    atomicAdd(&ws[WS_STATS + 16 + tid], lq[tid]);
  }
}

__global__ void bn_final_kernel(const float* __restrict__ gamma,
                                const float* __restrict__ beta,
                                float* __restrict__ ws) {
  int t = threadIdx.x;
  if (t < 15) {
    const float inv = 1.f / (float)kB;
    float mean = ws[WS_STATS + t] * inv;
    float var = ws[WS_STATS + 16 + t] * inv - mean * mean;
    float sc = gamma[t] * rsqrtf(var + 1e-5f);
    ws[WS_SS + t] = sc;
    ws[WS_SS + 16 + t] = beta[t] - mean * sc;
  }
}

__global__ __launch_bounds__(256, 2) void lstm_fused_kernel(
    const float* __restrict__ x, const float* __restrict__ w_ih0,
    const float* __restrict__ fc_b, const float* __restrict__ ws,
    float* __restrict__ out) {
  __shared__ ushort hc[32 * 128];   // [row][unit] XOR-swizzled, 8 KB
  __shared__ float xsf[32 * 17];    // 2.2 KB
  __shared__ float h1f[32 * 68];    // fp32 h1 at t=14 for FC, 8.7 KB

  const int tid = threadIdx.x;
  const int lane = tid & 63;
  const int wv = tid >> 6;
  const int grp = lane >> 4;
  const int l15 = lane & 15;
  const int u = wv * 16 + l15;

  // ---- per-block one-time hoists ----
  float b0g[4], b1g[4], w0g[4];
#pragma unroll
  for (int j = 0; j < 4; ++j) {
    b0g[j] = ws[WS_B0 + u + 64 * j];
    b1g[j] = ws[WS_B1 + u + 64 * j];
    w0g[j] = w_ih0[u + 64 * j];
  }
  const short8* bfr = (const short8*)(ws + WS_BF);
  short8 bL0[8], bL1[16];
#pragma unroll
  for (int ks = 0; ks < 2; ++ks)
#pragma unroll
    for (int j = 0; j < 4; ++j)
      bL0[ks * 4 + j] = bfr[(ks * 16 + wv + 4 * j) * 64 + lane];
#pragma unroll
  for (int ks = 0; ks < 4; ++ks)
#pragma unroll
    for (int j = 0; j < 4; ++j)
      bL1[ks * 4 + j] = bfr[(32 + ks * 16 + wv + 4 * j) * 64 + lane];

  auto ldA = [&](int mt, int ks) -> short8 {
    int row = l15 + 16 * mt;
    int k0 = (32 * ks + 8 * grp) ^ ((row & 7) << 3);
    return *(const short8*)&hc[row * 128 + k0];
  };

#pragma unroll 1
  for (int tile = blockIdx.x; tile < kTiles; tile += kGrid) {
    const int bm0 = tile * 32;

    // stage x (BN folded) + zero h state.  Safe vs prior tile: all hc/xsf
    // reads ended >=1 barrier ago; h1f (FC input) is a separate buffer.
    for (int i = tid; i < 32 * kT; i += 256) {
      float v = x[(size_t)bm0 * kT + i];
      int m = i / 15, tt = i - m * 15;
      xsf[m * 17 + tt] = v * ws[WS_SS + tt] + ws[WS_SS + 16 + tt];
    }
    for (int i = tid; i < 2048; i += 256) ((unsigned*)hc)[i] = 0u;

    float c0r[8], c1r[8];
#pragma unroll
    for (int i = 0; i < 8; ++i) { c0r[i] = 0.f; c1r[i] = 0.f; }

    __syncthreads();

#pragma unroll 1
    for (int t = 0; t < kT; ++t) {
      // ---------------- layer 0 ----------------
      f32x4 acc[2][4];
#pragma unroll
      for (int mt = 0; mt < 2; ++mt)
#pragma unroll
        for (int r = 0; r < 4; ++r) {
          float xv = xsf[(16 * mt + 4 * grp + r) * 17 + t];
#pragma unroll
          for (int j = 0; j < 4; ++j) acc[mt][j][r] = fmaf(xv, w0g[j], b0g[j]);
        }
#pragma unroll
      for (int ks = 0; ks < 2; ++ks) {
        short8 a0 = ldA(0, ks);
        short8 a1 = ldA(1, ks);
#pragma unroll
        for (int j = 0; j < 4; ++j) {
          acc[0][j] = __builtin_amdgcn_mfma_f32_16x16x32_bf16(a0, bL0[ks * 4 + j], acc[0][j], 0, 0, 0);
          acc[1][j] = __builtin_amdgcn_mfma_f32_16x16x32_bf16(a1, bL0[ks * 4 + j], acc[1][j], 0, 0, 0);
        }
      }
      __syncthreads();  // L0 A-reads done before h0_t overwrite
#pragma unroll
      for (int mt = 0; mt < 2; ++mt)
#pragma unroll
        for (int r = 0; r < 4; ++r) {
          int row = 16 * mt + 4 * grp + r;
          float zi = acc[mt][0][r], zf = acc[mt][1][r];
          float zg = acc[mt][2][r], zo = acc[mt][3][r];
          float ig = sigm(zi), fg = sigm(zf), gg = tanhx(zg), og = sigm(zo);
          float c = fmaf(fg, c0r[mt * 4 + r], ig * gg);
          c0r[mt * 4 + r] = c;
          float h = og * tanhx(c);
          hc[row * 128 + (u ^ ((row & 7) << 3))] = f2bf(h);
        }
      __syncthreads();  // h0_t visible (also orders prev-iter h1_t writes)

      // ---------------- layer 1 ----------------
#pragma unroll
      for (int mt = 0; mt < 2; ++mt)
#pragma unroll
        for (int j = 0; j < 4; ++j)
#pragma unroll
          for (int r = 0; r < 4; ++r) acc[mt][j][r] = b1g[j];
#pragma unroll
      for (int ks = 0; ks < 4; ++ks) {
        short8 a0 = ldA(0, ks);
        short8 a1 = ldA(1, ks);
#pragma unroll
        for (int j = 0; j < 4; ++j) {
          acc[0][j] = __builtin_amdgcn_mfma_f32_16x16x32_bf16(a0, bL1[ks * 4 + j], acc[0][j], 0, 0, 0);
          acc[1][j] = __builtin_amdgcn_mfma_f32_16x16x32_bf16(a1, bL1[ks * 4 + j], acc[1][j], 0, 0, 0);
        }
      }
      __syncthreads();  // L1 A-reads done before h1_t overwrite
#pragma unroll
      for (int mt = 0; mt < 2; ++mt)
#pragma unroll
        for (int r = 0; r < 4; ++r) {
          int row = 16 * mt + 4 * grp + r;
          float zi = acc[mt][0][r], zf = acc[mt][1][r];
          float zg = acc[mt][2][r], zo = acc[mt][3][r];
          float ig = sigm(zi), fg = sigm(zf), gg = tanhx(zg), og = sigm(zo);
          float c = fmaf(fg, c1r[mt * 4 + r], ig * gg);
          c1r[mt * 4 + r] = c;
          float h = og * tanhx(c);
          if (t < kT - 1) {
            hc[row * 128 + ((64 + u) ^ ((row & 7) << 3))] = f2bf(h);
          } else {
            h1f[row * 68 + u] = h;
          }
        }
      // no barrier: next L0 reads only h0 cols; h1 ordered by next bar2.
    }
    __syncthreads();  // h1f visible for FC

    // ---------------- FC + exact-erf GELU (fp32) ----------------
    {
      const int o = tid & 63;
      const int ms = tid >> 6;
      float yv[8];
      float fb = fc_b[o];
#pragma unroll
      for (int i = 0; i < 8; ++i) yv[i] = fb;
#pragma unroll 1
      for (int u0 = 0; u0 < 64; u0 += 4) {
        float q0 = ws[WS_FCT + (u0 + 0) * 64 + o];
        float q1 = ws[WS_FCT + (u0 + 1) * 64 + o];
        float q2 = ws[WS_FCT + (u0 + 2) * 64 + o];
        float q3 = ws[WS_FCT + (u0 + 3) * 64 + o];
#pragma unroll
        for (int i = 0; i < 8; ++i) {
          const float4 hq = *(const float4*)&h1f[(ms * 8 + i) * 68 + u0];
          yv[i] = fmaf(hq.x, q0, yv[i]);
          yv[i] = fmaf(hq.y, q1, yv[i]);
          yv[i] = fmaf(hq.z, q2, yv[i]);
          yv[i] = fmaf(hq.w, q3, yv[i]);
        }
      }
#pragma unroll
      for (int i = 0; i < 8; ++i) {
        float v = yv[i];
        float g = 0.5f * v * (1.f + erff(v * 0.70710678118654752f));
        out[(size_t)(bm0 + ms * 8 + i) * 64 + o] = g;
      }
    }
    // no barrier: next tile's hc/xsf writes don't touch h1f/out, and all
    // waves' hc/xsf reads for this tile ended before the barrier above.
  }
}

extern "C" void kernel_launch(void* const* d_in, const int* in_sizes, int n_in,
                              void* d_out, int out_size, void* d_ws, size_t ws_size,
                              hipStream_t stream) {
  const float* x = (const float*)d_in[0];
  const float* bn_gamma = (const float*)d_in[1];
  const float* bn_beta = (const float*)d_in[2];
  const float* w_ih0 = (const float*)d_in[3];
  const float* w_hh0 = (const float*)d_in[4];
  const float* b_ih0 = (const float*)d_in[5];
  const float* b_hh0 = (const float*)d_in[6];
  const float* w_ih1 = (const float*)d_in[7];
  const float* w_hh1 = (const float*)d_in[8];
  const float* b_ih1 = (const float*)d_in[9];
  const float* b_hh1 = (const float*)d_in[10];
  const float* fc_w = (const float*)d_in[11];
  const float* fc_b = (const float*)d_in[12];
  float* ws = (float*)d_ws;
  float* out = (float*)d_out;

  hipLaunchKernelGGL(prep_kernel, dim3(64), dim3(256), 0, stream,
                     w_hh0, w_ih1, w_hh1, b_ih0, b_hh0, b_ih1, b_hh1, fc_w, ws);
  hipLaunchKernelGGL(bn_sums_kernel, dim3(256), dim3(256), 0, stream, x, ws);
  hipLaunchKernelGGL(bn_final_kernel, dim3(1), dim3(64), 0, stream,
                     bn_gamma, bn_beta, ws);
  hipLaunchKernelGGL(lstm_fused_kernel, dim3(kGrid), dim3(256), 0, stream,
                     x, w_ih0, fc_b, ws, out);
}